// Round 15
// baseline (658.476 us; speedup 1.0000x reference)
//
#include <hip/hip_runtime.h>

typedef __attribute__((ext_vector_type(8))) short short8;
typedef __attribute__((ext_vector_type(8))) unsigned short ushort8;
typedef __attribute__((ext_vector_type(4))) float f32x4;

#define B_   32
#define L_   8192
#define IN_  512
#define HID_ 512
#define D3_  128

static __device__ __forceinline__ short f2bf(float f) {
    return __builtin_bit_cast(short, (__bf16)f);
}
static __device__ __forceinline__ unsigned short f2bfu(float f) {
    return __builtin_bit_cast(unsigned short, (__bf16)f);
}

// ---- prep: Wh (f32, D3 x HID) -> bf16, PRE-PERMUTED to MFMA lane order ----
// unit u = ks*512 + nt*64 + lane holds Wh[nt*16+(lane&15)][ks*32+(lane>>4)*8 ..+8]
// == exactly the 16B a lane needs as the MFMA B-operand for (step ks, col-blk nt).
__global__ void prep_whb2(const float* __restrict__ wh, unsigned short* __restrict__ whb2) {
    int u = blockIdx.x * 256 + threadIdx.x;   // 0..8191 (16B units)
    int lane = u & 63;
    int nt   = (u >> 6) & 7;
    int ks   = u >> 9;
    int col  = nt * 16 + (lane & 15);
    int k0   = ks * 32 + (lane >> 4) * 8;
    const float* src = wh + col * HID_ + k0;
    float4 a = *(const float4*)(src);
    float4 b = *(const float4*)(src + 4);
    unsigned short* d = whb2 + (size_t)u * 8;
    d[0] = f2bfu(a.x); d[1] = f2bfu(a.y); d[2] = f2bfu(a.z); d[3] = f2bfu(a.w);
    d[4] = f2bfu(b.x); d[5] = f2bfu(b.y); d[6] = f2bfu(b.z); d[7] = f2bfu(b.w);
}

// ---- prep: qpb[b][d] = inputs[b] . Wi[d] + bi[d] + bh[d]  (fp32) ----
__global__ void prep_qpb(const float* __restrict__ inputs, const float* __restrict__ Wi,
                         const float* __restrict__ bi, const float* __restrict__ bh,
                         float* __restrict__ qpb) {
    int b = blockIdx.x;
    int d = threadIdx.x;                 // 128 threads
    float acc = bi[d] + bh[d];
    const float* xr = inputs + b * IN_;
    const float* wr = Wi + d * IN_;
    #pragma unroll 4
    for (int i = 0; i < IN_; i += 4) {
        float4 x = *(const float4*)(xr + i);
        float4 w = *(const float4*)(wr + i);
        acc += x.x * w.x + x.y * w.y + x.z * w.z + x.w * w.w;
    }
    qpb[b * D3_ + d] = acc;
}

// ---- main ----
// H4 test: seven schedules (R6-R14) all pinned at 4.2-4.3 TB/s; the shared
// invariant was 8 waves/CU (LDS >=128 KiB -> 1 block/CU). R15 removes LDS
// ENTIRELY: B-frags are loaded per step straight from whb2 in L2 (128 KiB,
// resident in every XCD L2; ~2.1 GB aggregate L2 reads = 26% of L2 BW,
// TA ~42 B/cyc/CU < 64). 256-thread blocks + __launch_bounds__(256,4)
// -> 128-VGPR cap -> 16 waves/CU, 2x the wave-level latency hiding and
// ~64 KB/CU of outstanding A-reads. VGPR budget ~98 < 128 (qv/vv loaded
// per-tile in the epilogue, not held; sched_barrier(0) at step end stops
// the compiler hoisting next step's 8 B-loads = +32 regs = spill).
__global__ __launch_bounds__(256, 4) void attn_main(
    const float* __restrict__ ctx, const unsigned short* __restrict__ whb2,
    const float* __restrict__ qpb, const float* __restrict__ V,
    float* __restrict__ out)
{
    const int tid  = threadIdx.x;
    const int lane = tid & 63;
    const int w    = tid >> 6;           // wave 0..3, owns 16 rows per tile
    const int cb   = lane & 15;          // A-row / C-col index
    const int g    = lane >> 4;          // k-group 0..3

    // B-read base in L2: lane-linear (the permuted layout IS the lane order)
    const char* bwp = (const char*)whb2 + lane * 16;

    // A stream: lane (cb,g) reads row (base+cb), floats [kk*32 + g*8, +8)
    const float* pL = ctx + ((size_t)blockIdx.x * 256 + w * 16 + cb) * (size_t)HID_ + g * 8;

    const int b = blockIdx.x >> 5;       // 256 rows/block, 32 blocks per batch item

// one K-step: 8 B-loads from L2, A-ring cvt + prefetch (KK+2), 8 MFMAs.
// sched_barrier(0) at the end pins step boundaries (no cross-step B hoist).
#define DOSTEP(PA, PB, KK) { \
    const char* bp_ = bwp + (KK) * 8192; \
    const short8 b0 = *(const short8*)(bp_); \
    const short8 b1 = *(const short8*)(bp_ + 1024); \
    const short8 b2 = *(const short8*)(bp_ + 2048); \
    const short8 b3 = *(const short8*)(bp_ + 3072); \
    const short8 b4 = *(const short8*)(bp_ + 4096); \
    const short8 b5 = *(const short8*)(bp_ + 5120); \
    const short8 b6 = *(const short8*)(bp_ + 6144); \
    const short8 b7 = *(const short8*)(bp_ + 7168); \
    short8 aA; \
    aA[0] = f2bf(PA.x); aA[1] = f2bf(PA.y); aA[2] = f2bf(PA.z); aA[3] = f2bf(PA.w); \
    aA[4] = f2bf(PB.x); aA[5] = f2bf(PB.y); aA[6] = f2bf(PB.z); aA[7] = f2bf(PB.w); \
    if ((KK) < 14) { \
        PA = *(const float4*)(pT + ((KK) + 2) * 32); \
        PB = *(const float4*)(pT + ((KK) + 2) * 32 + 4); \
    } else { \
        PA = *(const float4*)(pN + ((KK) - 14) * 32); \
        PB = *(const float4*)(pN + ((KK) - 14) * 32 + 4); \
    } \
    acc[0] = __builtin_amdgcn_mfma_f32_16x16x32_bf16(aA, b0, acc[0], 0, 0, 0); \
    acc[1] = __builtin_amdgcn_mfma_f32_16x16x32_bf16(aA, b1, acc[1], 0, 0, 0); \
    acc[2] = __builtin_amdgcn_mfma_f32_16x16x32_bf16(aA, b2, acc[2], 0, 0, 0); \
    acc[3] = __builtin_amdgcn_mfma_f32_16x16x32_bf16(aA, b3, acc[3], 0, 0, 0); \
    acc[4] = __builtin_amdgcn_mfma_f32_16x16x32_bf16(aA, b4, acc[4], 0, 0, 0); \
    acc[5] = __builtin_amdgcn_mfma_f32_16x16x32_bf16(aA, b5, acc[5], 0, 0, 0); \
    acc[6] = __builtin_amdgcn_mfma_f32_16x16x32_bf16(aA, b6, acc[6], 0, 0, 0); \
    acc[7] = __builtin_amdgcn_mfma_f32_16x16x32_bf16(aA, b7, acc[7], 0, 0, 0); \
    __builtin_amdgcn_sched_barrier(0); }

    // prologue: A for steps 0 and 1 of tile 0
    float4 E0 = *(const float4*)(pL);        float4 E1 = *(const float4*)(pL + 4);
    float4 O0 = *(const float4*)(pL + 32);   float4 O1 = *(const float4*)(pL + 36);

    #pragma unroll 1
    for (int t = 0; t < 4; ++t) {        // 4 tiles of 64 rows (4 waves x 16)
        const float* pT = pL + (size_t)t * (64 * HID_);
        const float* pN = (t < 3) ? (pT + 64 * HID_) : pL;   // clamp: warm re-read

        f32x4 acc[8];
        #pragma unroll
        for (int nt = 0; nt < 8; ++nt) acc[nt] = (f32x4){0.f, 0.f, 0.f, 0.f};

        DOSTEP(E0, E1, 0)   DOSTEP(O0, O1, 1)
        DOSTEP(E0, E1, 2)   DOSTEP(O0, O1, 3)
        DOSTEP(E0, E1, 4)   DOSTEP(O0, O1, 5)
        DOSTEP(E0, E1, 6)   DOSTEP(O0, O1, 7)
        DOSTEP(E0, E1, 8)   DOSTEP(O0, O1, 9)
        DOSTEP(E0, E1, 10)  DOSTEP(O0, O1, 11)
        DOSTEP(E0, E1, 12)  DOSTEP(O0, O1, 13)
        DOSTEP(E0, E1, 14)  DOSTEP(O0, O1, 15)

        // epilogue: tanh(acc + q) . V, reduce over the 16 cb lanes.
        // qpb/V are L2-hot; loading them here (not holding 16 regs) keeps
        // the main loop under the 128-VGPR cap.
        float s0 = 0.f, s1 = 0.f, s2 = 0.f, s3 = 0.f;
        #pragma unroll
        for (int nt = 0; nt < 8; ++nt) {
            const float q  = qpb[b * D3_ + nt * 16 + cb];
            const float vn = V[nt * 16 + cb];
            s0 += (1.f - 2.f / (__expf(2.f * (acc[nt][0] + q)) + 1.f)) * vn;
            s1 += (1.f - 2.f / (__expf(2.f * (acc[nt][1] + q)) + 1.f)) * vn;
            s2 += (1.f - 2.f / (__expf(2.f * (acc[nt][2] + q)) + 1.f)) * vn;
            s3 += (1.f - 2.f / (__expf(2.f * (acc[nt][3] + q)) + 1.f)) * vn;
        }
        #pragma unroll
        for (int m = 1; m < 16; m <<= 1) {
            s0 += __shfl_xor(s0, m, 64);
            s1 += __shfl_xor(s1, m, 64);
            s2 += __shfl_xor(s2, m, 64);
            s3 += __shfl_xor(s3, m, 64);
        }
        if (cb == 0) {
            const size_t row0 = (size_t)blockIdx.x * 256 + (size_t)t * 64 + w * 16;
            const size_t off_ = row0 + (size_t)g * 4;
            *(float4*)(out + off_) = make_float4(s0, s1, s2, s3);
            *(float4*)(out + (size_t)B_ * L_ + off_) = make_float4(1.f, 1.f, 1.f, 1.f);
        }
    }
#undef DOSTEP
}

extern "C" void kernel_launch(void* const* d_in, const int* in_sizes, int n_in,
                              void* d_out, int out_size, void* d_ws, size_t ws_size,
                              hipStream_t stream) {
    const float* inputs  = (const float*)d_in[0];   // (32, 512)
    const float* context = (const float*)d_in[1];   // (32, 8192, 512)
    const float* Wi      = (const float*)d_in[2];   // (128, 512)
    const float* bi      = (const float*)d_in[3];   // (128,)
    const float* Wh      = (const float*)d_in[4];   // (128, 512)
    const float* bh      = (const float*)d_in[5];   // (128,)
    const float* V       = (const float*)d_in[6];   // (128,)
    float* out = (float*)d_out;                     // [att_row 262144][att 262144]

    unsigned short* whb2 = (unsigned short*)d_ws;                  // 128 KiB (permuted)
    float* qpb = (float*)((char*)d_ws + (size_t)D3_ * HID_ * 2);   // 16 KiB

    prep_whb2<<<32, 256, 0, stream>>>(Wh, whb2);
    prep_qpb<<<B_, D3_, 0, stream>>>(inputs, Wi, bi, bh, qpb);
    attn_main<<<1024, 256, 0, stream>>>(context, whb2, qpb, V, out);
}

// Round 16
// 471.531 us; speedup vs baseline: 1.3965x; 1.3965x over previous
//
#include <hip/hip_runtime.h>

typedef __attribute__((ext_vector_type(8))) short short8;
typedef __attribute__((ext_vector_type(8))) unsigned short ushort8;
typedef __attribute__((ext_vector_type(4))) float f32x4;

#define B_   32
#define L_   8192
#define IN_  512
#define HID_ 512
#define D3_  128

static __device__ __forceinline__ short f2bf(float f) {
    return __builtin_bit_cast(short, (__bf16)f);
}
static __device__ __forceinline__ unsigned short f2bfu(float f) {
    return __builtin_bit_cast(unsigned short, (__bf16)f);
}

// ---- prep: Wh (f32, D3 x HID) -> bf16, PRE-PERMUTED to MFMA lane order ----
// unit u = ks*512 + nt*64 + lane holds Wh[nt*16+(lane&15)][ks*32+(lane>>4)*8 ..+8]
// so the B-read is ds_read_b128 at whs + ks*8192 + nt*1024 + lane*16:
// contiguous 1 KiB per wave = bank-conflict-free (R9-proven correct+free).
__global__ void prep_whb2(const float* __restrict__ wh, unsigned short* __restrict__ whb2) {
    int u = blockIdx.x * 256 + threadIdx.x;   // 0..8191 (16B units)
    int lane = u & 63;
    int nt   = (u >> 6) & 7;
    int ks   = u >> 9;
    int col  = nt * 16 + (lane & 15);
    int k0   = ks * 32 + (lane >> 4) * 8;
    const float* src = wh + col * HID_ + k0;
    float4 a = *(const float4*)(src);
    float4 b = *(const float4*)(src + 4);
    unsigned short* d = whb2 + (size_t)u * 8;
    d[0] = f2bfu(a.x); d[1] = f2bfu(a.y); d[2] = f2bfu(a.z); d[3] = f2bfu(a.w);
    d[4] = f2bfu(b.x); d[5] = f2bfu(b.y); d[6] = f2bfu(b.z); d[7] = f2bfu(b.w);
}

// ---- prep: qpb[b][d] = inputs[b] . Wi[d] + bi[d] + bh[d]  (fp32) ----
__global__ void prep_qpb(const float* __restrict__ inputs, const float* __restrict__ Wi,
                         const float* __restrict__ bi, const float* __restrict__ bh,
                         float* __restrict__ qpb) {
    int b = blockIdx.x;
    int d = threadIdx.x;                 // 128 threads
    float acc = bi[d] + bh[d];
    const float* xr = inputs + b * IN_;
    const float* wr = Wi + d * IN_;
    #pragma unroll 4
    for (int i = 0; i < IN_; i += 4) {
        float4 x = *(const float4*)(xr + i);
        float4 w = *(const float4*)(wr + i);
        acc += x.x * w.x + x.y * w.y + x.z * w.z + x.w * w.w;
    }
    qpb[b * D3_ + d] = acc;
}

// ---- main ----
// The depth axis, finally tested clean. All ~125us variants held only
// 2 KB/wave outstanding (16 KB/CU / 2300cy latency = 7.1 B/cy = the observed
// 4.3 TB/s pin). R5/R8's "register rings spill" datapoints both carried
// 64-reg accumulators (32 rows/wave); with acc=32 (R13, no spill) a DEPTH-4
// named ring fits: acc 32 + ring 32 + aA 4 + B/addr transients ~20 ~= 90
// < the 128-cap. qv/vv load in the epilogue (L2-hot) instead of being held.
// No inline asm, no sched barriers: the compiler's per-named-reg vmcnt lets
// chunk c's use wait vmcnt(6), keeping 3 KB/wave = 24 KB/CU in flight
// (~10.4 B/cy ~ 6.4 TB/s potential). whs = R9's lane-linear read-only LDS.
__global__ __launch_bounds__(512) void attn_main(
    const float* __restrict__ ctx, const unsigned short* __restrict__ whb2,
    const float* __restrict__ qpb, const float* __restrict__ V,
    float* __restrict__ out)
{
    __shared__ unsigned short whs[D3_ * HID_];   // 128 KiB: [ks 16][nt 8][1024B]

    const int tid = threadIdx.x;

    // stage whs: pure linear copy (whb2 already permuted) -- conflict-free
    #pragma unroll
    for (int p = 0; p < 16; ++p) {
        int m = p * 512 + tid;
        *(ushort8*)((char*)whs + (size_t)m * 16) = *(const ushort8*)(whb2 + (size_t)m * 8);
    }
    __syncthreads();

    const int lane = tid & 63;
    const int w    = tid >> 6;           // wave 0..7, owns 16 rows per tile
    const int cb   = lane & 15;          // A-row / C-col index
    const int g    = lane >> 4;          // k-group 0..3

    // B-read base (lane-linear, conflict-free, read-only for the whole kernel)
    const char* bptr = (const char*)whs + lane * 16;

    // A stream: lane (cb,g) reads row (base+cb), floats [kk*32 + g*8, +8)
    const float* pL = ctx + ((size_t)blockIdx.x * 1024 + w * 16 + cb) * (size_t)HID_ + g * 8;

    const int b = blockIdx.x >> 3;       // 1024 rows per block, 8 blocks per batch

// one K-step: consume ring slot (RA,RB) for step KK, refill it with step
// KK+4 (from pT, or pN once KK+4 crosses the tile), 8 x (ds_read B; MFMA).
// No pinning: the compiler interleaves ds_read/MFMA with fine lgkmcnt and
// places a counted vmcnt before the cvt (leaves ~6 loads = 3 KB in flight).
#define STEPK(RA, RB, KK) { \
    short8 aA; \
    aA[0] = f2bf(RA.x); aA[1] = f2bf(RA.y); aA[2] = f2bf(RA.z); aA[3] = f2bf(RA.w); \
    aA[4] = f2bf(RB.x); aA[5] = f2bf(RB.y); aA[6] = f2bf(RB.z); aA[7] = f2bf(RB.w); \
    if ((KK) < 12) { \
        RA = *(const float4*)(pT + ((KK) + 4) * 32); \
        RB = *(const float4*)(pT + ((KK) + 4) * 32 + 4); \
    } else { \
        RA = *(const float4*)(pN + ((KK) - 12) * 32); \
        RB = *(const float4*)(pN + ((KK) - 12) * 32 + 4); \
    } \
    _Pragma("unroll") \
    for (int nt = 0; nt < 8; ++nt) { \
        const short8 bb = *(const short8*)(bptr + (KK) * 8192 + nt * 1024); \
        acc[nt] = __builtin_amdgcn_mfma_f32_16x16x32_bf16(aA, bb, acc[nt], 0, 0, 0); \
    } }

    // prologue: ring slots 0..3 = steps 0..3 of tile 0
    float4 R0a = *(const float4*)(pL);         float4 R0b = *(const float4*)(pL + 4);
    float4 R1a = *(const float4*)(pL + 32);    float4 R1b = *(const float4*)(pL + 36);
    float4 R2a = *(const float4*)(pL + 64);    float4 R2b = *(const float4*)(pL + 68);
    float4 R3a = *(const float4*)(pL + 96);    float4 R3b = *(const float4*)(pL + 100);

    #pragma unroll 1
    for (int t = 0; t < 8; ++t) {        // 8 tiles of 128 rows
        const float* pT = pL + (size_t)t * (128 * HID_);
        const float* pN = (t < 7) ? (pT + 128 * HID_) : pL;   // clamp: warm re-read

        f32x4 acc[8];
        #pragma unroll
        for (int nt = 0; nt < 8; ++nt) acc[nt] = (f32x4){0.f, 0.f, 0.f, 0.f};

        STEPK(R0a, R0b, 0)   STEPK(R1a, R1b, 1)
        STEPK(R2a, R2b, 2)   STEPK(R3a, R3b, 3)
        STEPK(R0a, R0b, 4)   STEPK(R1a, R1b, 5)
        STEPK(R2a, R2b, 6)   STEPK(R3a, R3b, 7)
        STEPK(R0a, R0b, 8)   STEPK(R1a, R1b, 9)
        STEPK(R2a, R2b, 10)  STEPK(R3a, R3b, 11)
        STEPK(R0a, R0b, 12)  STEPK(R1a, R1b, 13)
        STEPK(R2a, R2b, 14)  STEPK(R3a, R3b, 15)

        // epilogue: tanh(acc + q) . V, reduce over the 16 cb lanes.
        // qpb/V are L2-hot: load here instead of holding 16 regs in the loop.
        float s0 = 0.f, s1 = 0.f, s2 = 0.f, s3 = 0.f;
        #pragma unroll
        for (int nt = 0; nt < 8; ++nt) {
            const float q  = qpb[b * D3_ + nt * 16 + cb];
            const float vn = V[nt * 16 + cb];
            s0 += (1.f - 2.f / (__expf(2.f * (acc[nt][0] + q)) + 1.f)) * vn;
            s1 += (1.f - 2.f / (__expf(2.f * (acc[nt][1] + q)) + 1.f)) * vn;
            s2 += (1.f - 2.f / (__expf(2.f * (acc[nt][2] + q)) + 1.f)) * vn;
            s3 += (1.f - 2.f / (__expf(2.f * (acc[nt][3] + q)) + 1.f)) * vn;
        }
        #pragma unroll
        for (int m = 1; m < 16; m <<= 1) {
            s0 += __shfl_xor(s0, m, 64);
            s1 += __shfl_xor(s1, m, 64);
            s2 += __shfl_xor(s2, m, 64);
            s3 += __shfl_xor(s3, m, 64);
        }
        if (cb == 0) {
            const size_t row0 = (size_t)blockIdx.x * 1024 + (size_t)t * 128 + w * 16;
            const size_t off_ = row0 + (size_t)g * 4;
            *(float4*)(out + off_) = make_float4(s0, s1, s2, s3);
            *(float4*)(out + (size_t)B_ * L_ + off_) = make_float4(1.f, 1.f, 1.f, 1.f);
        }
    }
#undef STEPK
}

extern "C" void kernel_launch(void* const* d_in, const int* in_sizes, int n_in,
                              void* d_out, int out_size, void* d_ws, size_t ws_size,
                              hipStream_t stream) {
    const float* inputs  = (const float*)d_in[0];   // (32, 512)
    const float* context = (const float*)d_in[1];   // (32, 8192, 512)
    const float* Wi      = (const float*)d_in[2];   // (128, 512)
    const float* bi      = (const float*)d_in[3];   // (128,)
    const float* Wh      = (const float*)d_in[4];   // (128, 512)
    const float* bh      = (const float*)d_in[5];   // (128,)
    const float* V       = (const float*)d_in[6];   // (128,)
    float* out = (float*)d_out;                     // [att_row 262144][att 262144]

    unsigned short* whb2 = (unsigned short*)d_ws;                  // 128 KiB (permuted)
    float* qpb = (float*)((char*)d_ws + (size_t)D3_ * HID_ * 2);   // 16 KiB

    prep_whb2<<<32, 256, 0, stream>>>(Wh, whb2);
    prep_qpb<<<B_, D3_, 0, stream>>>(inputs, Wi, bi, bh, qpb);
    attn_main<<<256, 512, 0, stream>>>(context, whb2, qpb, V, out);
}

// Round 17
// 145.794 us; speedup vs baseline: 4.5165x; 3.2342x over previous
//
#include <hip/hip_runtime.h>

typedef __attribute__((ext_vector_type(8))) short short8;
typedef __attribute__((ext_vector_type(8))) unsigned short ushort8;
typedef __attribute__((ext_vector_type(4))) float f32x4;

#define B_   32
#define L_   8192
#define IN_  512
#define HID_ 512
#define D3_  128

static __device__ __forceinline__ short f2bf(float f) {
    return __builtin_bit_cast(short, (__bf16)f);
}
static __device__ __forceinline__ unsigned short f2bfu(float f) {
    return __builtin_bit_cast(unsigned short, (__bf16)f);
}

// ---- prep: Wh (f32, D3 x HID) -> bf16, PRE-PERMUTED to MFMA lane order ----
// unit u = ks*512 + nt*64 + lane holds Wh[nt*16+(lane&15)][ks*32+(lane>>4)*8 ..+8]
// so the B-read is ds_read_b128 at whs + ks*8192 + nt*1024 + lane*16:
// contiguous 1 KiB per wave = bank-conflict-free (R9-proven).
__global__ void prep_whb2(const float* __restrict__ wh, unsigned short* __restrict__ whb2) {
    int u = blockIdx.x * 256 + threadIdx.x;   // 0..8191 (16B units)
    int lane = u & 63;
    int nt   = (u >> 6) & 7;
    int ks   = u >> 9;
    int col  = nt * 16 + (lane & 15);
    int k0   = ks * 32 + (lane >> 4) * 8;
    const float* src = wh + col * HID_ + k0;
    float4 a = *(const float4*)(src);
    float4 b = *(const float4*)(src + 4);
    unsigned short* d = whb2 + (size_t)u * 8;
    d[0] = f2bfu(a.x); d[1] = f2bfu(a.y); d[2] = f2bfu(a.z); d[3] = f2bfu(a.w);
    d[4] = f2bfu(b.x); d[5] = f2bfu(b.y); d[6] = f2bfu(b.z); d[7] = f2bfu(b.w);
}

// ---- prep: qpb[b][d] = inputs[b] . Wi[d] + bi[d] + bh[d]  (fp32) ----
__global__ void prep_qpb(const float* __restrict__ inputs, const float* __restrict__ Wi,
                         const float* __restrict__ bi, const float* __restrict__ bh,
                         float* __restrict__ qpb) {
    int b = blockIdx.x;
    int d = threadIdx.x;                 // 128 threads
    float acc = bi[d] + bh[d];
    const float* xr = inputs + b * IN_;
    const float* wr = Wi + d * IN_;
    #pragma unroll 4
    for (int i = 0; i < IN_; i += 4) {
        float4 x = *(const float4*)(xr + i);
        float4 w = *(const float4*)(wr + i);
        acc += x.x * w.x + x.y * w.y + x.z * w.z + x.w * w.w;
    }
    qpb[b * D3_ + d] = acc;
}

// ---- main ----
// The last untested cell of the transport x schedule matrix: plain
// global_load -> depth-2 register ring, COMPILER-scheduled (no pins).
// R13 tested this transport but 1:1 DS_READ:MFMA sched_group_barrier pins
// serialized each MFMA behind its ds_read (~130cy x128 = its whole deficit).
// Plain loads ride the MSHR queue (copy ubench path, 6.3 TB/s) instead of
// the LDS-DMA queue every 4.3 TB/s-pinned variant used; the compiler's
// counted vmcnt on named regs leaves ~4 KB/wave = 32 KB/CU in flight.
// Spill guards: acc 32 + ring 16 only (depth-4 spilled in R16); qv/vv
// loaded in the epilogue; sched_barrier(0) at step END stops cross-step
// B-transient hoisting; the one after the A-prefetch keeps load issue at
// step top. No inline-asm waits anywhere.
__global__ __launch_bounds__(512) void attn_main(
    const float* __restrict__ ctx, const unsigned short* __restrict__ whb2,
    const float* __restrict__ qpb, const float* __restrict__ V,
    float* __restrict__ out)
{
    __shared__ unsigned short whs[D3_ * HID_];   // 128 KiB: [ks 16][nt 8][1024B]

    const int tid = threadIdx.x;

    // stage whs: pure linear copy (whb2 already permuted) -- conflict-free
    #pragma unroll
    for (int p = 0; p < 16; ++p) {
        int m = p * 512 + tid;
        *(ushort8*)((char*)whs + (size_t)m * 16) = *(const ushort8*)(whb2 + (size_t)m * 8);
    }
    __syncthreads();

    const int lane = tid & 63;
    const int w    = tid >> 6;           // wave 0..7, owns 16 rows per tile
    const int cb   = lane & 15;          // A-row / C-col index
    const int g    = lane >> 4;          // k-group 0..3

    // B-read base (lane-linear, conflict-free, read-only all kernel)
    const char* bptr = (const char*)whs + lane * 16;

    // A stream: lane (cb,g) reads row (base+cb), floats [kk*32 + g*8, +8)
    const float* pL = ctx + ((size_t)blockIdx.x * 1024 + w * 16 + cb) * (size_t)HID_ + g * 8;

    const int b = blockIdx.x >> 3;       // 1024 rows per block, 8 blocks per batch

// one K-step: cvt ring slot -> aA; refill slot with step KK+2 (issue pinned
// to step top); 8 x {ds_read B; MFMA} left to the compiler; step-end barrier
// only (prevents next step's B ds_reads from being hoisted = reg blowup).
#define DOSTEP(PA, PB, KK) { \
    short8 aA; \
    aA[0] = f2bf(PA.x); aA[1] = f2bf(PA.y); aA[2] = f2bf(PA.z); aA[3] = f2bf(PA.w); \
    aA[4] = f2bf(PB.x); aA[5] = f2bf(PB.y); aA[6] = f2bf(PB.z); aA[7] = f2bf(PB.w); \
    if ((KK) < 14) { \
        PA = *(const float4*)(pT + ((KK) + 2) * 32); \
        PB = *(const float4*)(pT + ((KK) + 2) * 32 + 4); \
    } else { \
        PA = *(const float4*)(pN + ((KK) - 14) * 32); \
        PB = *(const float4*)(pN + ((KK) - 14) * 32 + 4); \
    } \
    __builtin_amdgcn_sched_barrier(0); \
    _Pragma("unroll") \
    for (int nt = 0; nt < 8; ++nt) { \
        const short8 bb = *(const short8*)(bptr + (KK) * 8192 + nt * 1024); \
        acc[nt] = __builtin_amdgcn_mfma_f32_16x16x32_bf16(aA, bb, acc[nt], 0, 0, 0); \
    } \
    __builtin_amdgcn_sched_barrier(0); }

    // prologue: ring = steps 0 and 1 of tile 0
    float4 E0 = *(const float4*)(pL);        float4 E1 = *(const float4*)(pL + 4);
    float4 O0 = *(const float4*)(pL + 32);   float4 O1 = *(const float4*)(pL + 36);

    #pragma unroll 1
    for (int t = 0; t < 8; ++t) {        // 8 tiles of 128 rows
        const float* pT = pL + (size_t)t * (128 * HID_);
        const float* pN = (t < 7) ? (pT + 128 * HID_) : pL;   // clamp: warm re-read

        f32x4 acc[8];
        #pragma unroll
        for (int nt = 0; nt < 8; ++nt) acc[nt] = (f32x4){0.f, 0.f, 0.f, 0.f};

        DOSTEP(E0, E1, 0)   DOSTEP(O0, O1, 1)
        DOSTEP(E0, E1, 2)   DOSTEP(O0, O1, 3)
        DOSTEP(E0, E1, 4)   DOSTEP(O0, O1, 5)
        DOSTEP(E0, E1, 6)   DOSTEP(O0, O1, 7)
        DOSTEP(E0, E1, 8)   DOSTEP(O0, O1, 9)
        DOSTEP(E0, E1, 10)  DOSTEP(O0, O1, 11)
        DOSTEP(E0, E1, 12)  DOSTEP(O0, O1, 13)
        DOSTEP(E0, E1, 14)  DOSTEP(O0, O1, 15)

        // epilogue: tanh(acc + q) . V, reduce over the 16 cb lanes.
        // qpb/V are L2-hot: loaded here, not held across the main loop.
        float s0 = 0.f, s1 = 0.f, s2 = 0.f, s3 = 0.f;
        #pragma unroll
        for (int nt = 0; nt < 8; ++nt) {
            const float q  = qpb[b * D3_ + nt * 16 + cb];
            const float vn = V[nt * 16 + cb];
            s0 += (1.f - 2.f / (__expf(2.f * (acc[nt][0] + q)) + 1.f)) * vn;
            s1 += (1.f - 2.f / (__expf(2.f * (acc[nt][1] + q)) + 1.f)) * vn;
            s2 += (1.f - 2.f / (__expf(2.f * (acc[nt][2] + q)) + 1.f)) * vn;
            s3 += (1.f - 2.f / (__expf(2.f * (acc[nt][3] + q)) + 1.f)) * vn;
        }
        #pragma unroll
        for (int m = 1; m < 16; m <<= 1) {
            s0 += __shfl_xor(s0, m, 64);
            s1 += __shfl_xor(s1, m, 64);
            s2 += __shfl_xor(s2, m, 64);
            s3 += __shfl_xor(s3, m, 64);
        }
        if (cb == 0) {
            const size_t row0 = (size_t)blockIdx.x * 1024 + (size_t)t * 128 + w * 16;
            const size_t off_ = row0 + (size_t)g * 4;
            *(float4*)(out + off_) = make_float4(s0, s1, s2, s3);
            *(float4*)(out + (size_t)B_ * L_ + off_) = make_float4(1.f, 1.f, 1.f, 1.f);
        }
    }
#undef DOSTEP
}

extern "C" void kernel_launch(void* const* d_in, const int* in_sizes, int n_in,
                              void* d_out, int out_size, void* d_ws, size_t ws_size,
                              hipStream_t stream) {
    const float* inputs  = (const float*)d_in[0];   // (32, 512)
    const float* context = (const float*)d_in[1];   // (32, 8192, 512)
    const float* Wi      = (const float*)d_in[2];   // (128, 512)
    const float* bi      = (const float*)d_in[3];   // (128,)
    const float* Wh      = (const float*)d_in[4];   // (128, 512)
    const float* bh      = (const float*)d_in[5];   // (128,)
    const float* V       = (const float*)d_in[6];   // (128,)
    float* out = (float*)d_out;                     // [att_row 262144][att 262144]

    unsigned short* whb2 = (unsigned short*)d_ws;                  // 128 KiB (permuted)
    float* qpb = (float*)((char*)d_ws + (size_t)D3_ * HID_ * 2);   // 16 KiB

    prep_whb2<<<32, 256, 0, stream>>>(Wh, whb2);
    prep_qpb<<<B_, D3_, 0, stream>>>(inputs, Wi, bi, bh, qpb);
    attn_main<<<256, 512, 0, stream>>>(context, whb2, qpb, V, out);
}

// Round 18
// 131.922 us; speedup vs baseline: 4.9914x; 1.1052x over previous
//
#include <hip/hip_runtime.h>

typedef __attribute__((ext_vector_type(8))) short short8;
typedef __attribute__((ext_vector_type(8))) unsigned short ushort8;
typedef __attribute__((ext_vector_type(4))) float f32x4;

#define B_   32
#define L_   8192
#define IN_  512
#define HID_ 512
#define D3_  128

static __device__ __forceinline__ short f2bf(float f) {
    return __builtin_bit_cast(short, (__bf16)f);
}
static __device__ __forceinline__ unsigned short f2bfu(float f) {
    return __builtin_bit_cast(unsigned short, (__bf16)f);
}

// async global->LDS, 16B per lane (dest = wave-uniform base + lane*16)
static __device__ __forceinline__ void gload_lds16(const void* g, void* l) {
    __builtin_amdgcn_global_load_lds(
        (const __attribute__((address_space(1))) unsigned int*)g,
        (__attribute__((address_space(3))) unsigned int*)l, 16, 0, 0);
}

// ---- prep: Wh (f32, D3 x HID) -> bf16, PRE-PERMUTED to MFMA lane order ----
__global__ void prep_whb2(const float* __restrict__ wh, unsigned short* __restrict__ whb2) {
    int u = blockIdx.x * 256 + threadIdx.x;   // 0..8191 (16B units)
    int lane = u & 63;
    int nt   = (u >> 6) & 7;
    int ks   = u >> 9;
    int col  = nt * 16 + (lane & 15);
    int k0   = ks * 32 + (lane >> 4) * 8;
    const float* src = wh + col * HID_ + k0;
    float4 a = *(const float4*)(src);
    float4 b = *(const float4*)(src + 4);
    unsigned short* d = whb2 + (size_t)u * 8;
    d[0] = f2bfu(a.x); d[1] = f2bfu(a.y); d[2] = f2bfu(a.z); d[3] = f2bfu(a.w);
    d[4] = f2bfu(b.x); d[5] = f2bfu(b.y); d[6] = f2bfu(b.z); d[7] = f2bfu(b.w);
}

// ---- prep: qpb[b][d] = inputs[b] . Wi[d] + bi[d] + bh[d]  (fp32) ----
__global__ void prep_qpb(const float* __restrict__ inputs, const float* __restrict__ Wi,
                         const float* __restrict__ bi, const float* __restrict__ bh,
                         float* __restrict__ qpb) {
    int b = blockIdx.x;
    int d = threadIdx.x;                 // 128 threads
    float acc = bi[d] + bh[d];
    const float* xr = inputs + b * IN_;
    const float* wr = Wi + d * IN_;
    #pragma unroll 4
    for (int i = 0; i < IN_; i += 4) {
        float4 x = *(const float4*)(xr + i);
        float4 w = *(const float4*)(wr + i);
        acc += x.x * w.x + x.y * w.y + x.z * w.z + x.w * w.w;
    }
    qpb[b * D3_ + d] = acc;
}

// ---- main ----
// MIXED-TRANSPORT test of H3 (per-CU LDS-DMA queue depth cap). DMA-only
// variants pin at 4.3 TB/s (R6/R9/R10/R11/R14); pure plain-load is worse
// for its own reasons (R13/R17). The two transports use DIFFERENT HW
// queues: each wave's 2 KB chunk is split 1 KB DMA->LDS (rows 0-7,
// sector-dense) + 1 KB plain global_load->E/O register ring (rows 8-15;
// lanes cb and cb+8 load duplicate addresses -> TA dedup, no extra
// traffic). Per-lane cndmask select picks LDS vs reg A-frag. Uniform
// ledger: 3 VMEM issues/step (chunk &127 tail clamp) -> vmcnt(5) guards
// the DMA chunk; compiler's counted waits guard the plain regs.
__global__ __launch_bounds__(512) void attn_main(
    const float* __restrict__ ctx, const unsigned short* __restrict__ whb2,
    const float* __restrict__ qpb, const float* __restrict__ V,
    float* __restrict__ out)
{
    __shared__ unsigned short whs[D3_ * HID_];   // 128 KiB: [ks 16][nt 8][1024B]
    __shared__ float cbuf[2][2048];              // 16 KiB: [par][wave 8][1024B]

    const int tid = threadIdx.x;

    // stage whs: pure linear copy (whb2 already permuted) -- conflict-free
    #pragma unroll
    for (int p = 0; p < 16; ++p) {
        int m = p * 512 + tid;
        *(ushort8*)((char*)whs + (size_t)m * 16) = *(const ushort8*)(whb2 + (size_t)m * 8);
    }
    __syncthreads();

    const int lane = tid & 63;
    const int w    = tid >> 6;           // wave 0..7, owns 16 rows per tile
    const int cb   = lane & 15;          // A-row / C-col index
    const int g    = lane >> 4;          // k-group 0..3

    // B-read base (lane-linear, conflict-free, read-only all kernel)
    const char* bptr = (const char*)whs + lane * 16;

    // DMA half (rows 0-7): sector-dense source, lane-linear LDS dest
    const int srow = lane >> 3;                      // row 0..7 this lane sources
    const int spce = (lane & 7) ^ srow;              // 16B piece within 128B
    const float* gsrcD = ctx
        + ((size_t)blockIdx.x * 1024 + w * 16 + srow) * (size_t)HID_ + spce * 4;
    char* ldst = (char*)cbuf + w * 1024 + lane * 16;

    // LDS A-read (meaningful for lanes cb<8): row cb&7, pieces 2g/2g+1
    const char* abase = (const char*)cbuf + w * 1024 + (cb & 7) * 128;
    const int aoff0 = (((2 * g)     ^ (cb & 7)) << 4);
    const int aoff1 = (((2 * g + 1) ^ (cb & 7)) << 4);

    // plain half (rows 8-15): lane loads row 8+(cb&7), its own 2x16B.
    // lanes cb<8 and cb>=8 load identical addresses (dedup at the TA).
    const float* pP = ctx
        + ((size_t)blockIdx.x * 1024 + w * 16 + 8 + (cb & 7)) * (size_t)HID_ + g * 8;

    const int b = blockIdx.x >> 3;       // 1024 rows per block, 8 blocks per batch

#define CHOFF(CC) ((size_t)(((CC) & 127) >> 4) * (128 * HID_) + (((CC) & 127) & 15) * 32)

    // prologue: DMA chunks 0,1 + plain ring chunks 0,1
    gload_lds16(gsrcD + CHOFF(0), ldst);
    gload_lds16(gsrcD + CHOFF(1), ldst + 8192);
    float4 PE0 = *(const float4*)(pP + CHOFF(0));
    float4 PE1 = *(const float4*)(pP + CHOFF(0) + 4);
    float4 PO0 = *(const float4*)(pP + CHOFF(1));
    float4 PO1 = *(const float4*)(pP + CHOFF(1) + 4);

// one K-step for chunk C with plain-ring pair (PA,PB):
//  vmcnt(5) -> DMA(C) landed; LDS A-read; lgkmcnt(0); re-issue DMA(C+2) and
//  plain(C+2) into the same pair; per-lane select; 8 x MFMA.
#define DOSTEP(PA, PB, C) { \
    asm volatile("s_waitcnt vmcnt(5)" ::: "memory"); \
    const char* ap_ = abase + (((C) & 1) ? 8192 : 0); \
    const f32x4 l0_ = *(const f32x4*)(ap_ + aoff0); \
    const f32x4 l1_ = *(const f32x4*)(ap_ + aoff1); \
    asm volatile("s_waitcnt lgkmcnt(0)" ::: "memory"); \
    __builtin_amdgcn_sched_barrier(0); \
    gload_lds16(gsrcD + CHOFF((C) + 2), ldst + ((((C) + 2) & 1) ? 8192 : 0)); \
    const float4 w0_ = (cb < 8) ? make_float4(l0_[0], l0_[1], l0_[2], l0_[3]) : PA; \
    const float4 w1_ = (cb < 8) ? make_float4(l1_[0], l1_[1], l1_[2], l1_[3]) : PB; \
    PA = *(const float4*)(pP + CHOFF((C) + 2)); \
    PB = *(const float4*)(pP + CHOFF((C) + 2) + 4); \
    __builtin_amdgcn_sched_barrier(0); \
    short8 aA; \
    aA[0] = f2bf(w0_.x); aA[1] = f2bf(w0_.y); aA[2] = f2bf(w0_.z); aA[3] = f2bf(w0_.w); \
    aA[4] = f2bf(w1_.x); aA[5] = f2bf(w1_.y); aA[6] = f2bf(w1_.z); aA[7] = f2bf(w1_.w); \
    _Pragma("unroll") \
    for (int nt = 0; nt < 8; ++nt) { \
        const short8 bb = *(const short8*)(bptr + ((C) & 15) * 8192 + nt * 1024); \
        acc[nt] = __builtin_amdgcn_mfma_f32_16x16x32_bf16(aA, bb, acc[nt], 0, 0, 0); \
    } \
    __builtin_amdgcn_sched_barrier(0); }

    #pragma unroll 1
    for (int t = 0; t < 8; ++t) {        // 8 tiles of 128 rows
        f32x4 acc[8];
        #pragma unroll
        for (int nt = 0; nt < 8; ++nt) acc[nt] = (f32x4){0.f, 0.f, 0.f, 0.f};

        DOSTEP(PE0, PE1, t * 16 + 0)   DOSTEP(PO0, PO1, t * 16 + 1)
        DOSTEP(PE0, PE1, t * 16 + 2)   DOSTEP(PO0, PO1, t * 16 + 3)
        DOSTEP(PE0, PE1, t * 16 + 4)   DOSTEP(PO0, PO1, t * 16 + 5)
        DOSTEP(PE0, PE1, t * 16 + 6)   DOSTEP(PO0, PO1, t * 16 + 7)
        DOSTEP(PE0, PE1, t * 16 + 8)   DOSTEP(PO0, PO1, t * 16 + 9)
        DOSTEP(PE0, PE1, t * 16 + 10)  DOSTEP(PO0, PO1, t * 16 + 11)
        DOSTEP(PE0, PE1, t * 16 + 12)  DOSTEP(PO0, PO1, t * 16 + 13)
        DOSTEP(PE0, PE1, t * 16 + 14)  DOSTEP(PO0, PO1, t * 16 + 15)

        // epilogue: tanh(acc + q) . V, reduce over the 16 cb lanes.
        // qpb/V are L2-hot: loaded here, not held across the main loop.
        float s0 = 0.f, s1 = 0.f, s2 = 0.f, s3 = 0.f;
        #pragma unroll
        for (int nt = 0; nt < 8; ++nt) {
            const float q  = qpb[b * D3_ + nt * 16 + cb];
            const float vn = V[nt * 16 + cb];
            s0 += (1.f - 2.f / (__expf(2.f * (acc[nt][0] + q)) + 1.f)) * vn;
            s1 += (1.f - 2.f / (__expf(2.f * (acc[nt][1] + q)) + 1.f)) * vn;
            s2 += (1.f - 2.f / (__expf(2.f * (acc[nt][2] + q)) + 1.f)) * vn;
            s3 += (1.f - 2.f / (__expf(2.f * (acc[nt][3] + q)) + 1.f)) * vn;
        }
        #pragma unroll
        for (int m = 1; m < 16; m <<= 1) {
            s0 += __shfl_xor(s0, m, 64);
            s1 += __shfl_xor(s1, m, 64);
            s2 += __shfl_xor(s2, m, 64);
            s3 += __shfl_xor(s3, m, 64);
        }
        if (cb == 0) {
            const size_t row0 = (size_t)blockIdx.x * 1024 + (size_t)t * 128 + w * 16;
            const size_t off_ = row0 + (size_t)g * 4;
            *(float4*)(out + off_) = make_float4(s0, s1, s2, s3);
            *(float4*)(out + (size_t)B_ * L_ + off_) = make_float4(1.f, 1.f, 1.f, 1.f);
        }
    }
#undef DOSTEP
#undef CHOFF
}

extern "C" void kernel_launch(void* const* d_in, const int* in_sizes, int n_in,
                              void* d_out, int out_size, void* d_ws, size_t ws_size,
                              hipStream_t stream) {
    const float* inputs  = (const float*)d_in[0];   // (32, 512)
    const float* context = (const float*)d_in[1];   // (32, 8192, 512)
    const float* Wi      = (const float*)d_in[2];   // (128, 512)
    const float* bi      = (const float*)d_in[3];   // (128,)
    const float* Wh      = (const float*)d_in[4];   // (128, 512)
    const float* bh      = (const float*)d_in[5];   // (128,)
    const float* V       = (const float*)d_in[6];   // (128,)
    float* out = (float*)d_out;                     // [att_row 262144][att 262144]

    unsigned short* whb2 = (unsigned short*)d_ws;                  // 128 KiB (permuted)
    float* qpb = (float*)((char*)d_ws + (size_t)D3_ * HID_ * 2);   // 16 KiB

    prep_whb2<<<32, 256, 0, stream>>>(Wh, whb2);
    prep_qpb<<<B_, D3_, 0, stream>>>(inputs, Wi, bi, bh, qpb);
    attn_main<<<256, 512, 0, stream>>>(context, whb2, qpb, V, out);
}